// Round 8
// baseline (203.109 us; speedup 1.0000x reference)
//
#include <hip/hip_runtime.h>
#include <hip/hip_bf16.h>
#include <math.h>

#define NCLS 256
#define PER_CLASS 128
#define NSUP 5
#define NQRY 123              // PER_CLASS - NSUP
#define NVIEW 2
#define DD 384
#define NQ_TOT (NCLS * NQRY)  // 31488
#define BM 64                 // queries per block
#define BK 32                 // k-tile (elems)
#define NKT (DD / BK)         // 12
#define PSTR 40               // P LDS row stride in ushorts (32 data + 8 pad; 2-way-max banks, r2-proven)

typedef __attribute__((ext_vector_type(8))) short short8;
typedef __attribute__((ext_vector_type(4))) float floatx4;

union FragU { uint4 u; short8 s; };
union PkU { __hip_bfloat162 b2; unsigned int u; };

__device__ __forceinline__ unsigned int cvt2bf(float lo, float hi) {
    PkU p;
    p.b2 = __float22bfloat162_rn(make_float2(lo, hi));
    return p.u;
}

// barrier WITHOUT the vmcnt(0) drain: LDS writes visible, global loads keep flying
#define BARRIER() asm volatile("s_waitcnt lgkmcnt(0)\n\ts_barrier" ::: "memory")

// ---------- kernel 1: prototypes -> bf16 + y2, fused (verified) ----------
__global__ __launch_bounds__(384) void proto_kernel(const float* __restrict__ reps,
                                                    ushort* __restrict__ pbf,
                                                    float* __restrict__ y2) {
    __shared__ float wp[6];
    const int b = blockIdx.x;          // v*256 + c
    const int c = b & 255, v = b >> 8;
    const int d = threadIdx.x;         // 0..383
    const float* p = reps + ((size_t)(c * PER_CLASS) * NVIEW + v) * DD + d;
    float s = 0.f;
#pragma unroll
    for (int k = 0; k < NSUP; ++k) s += p[(size_t)k * NVIEW * DD];
    s *= 0.2f;
    __hip_bfloat16 h = __float2bfloat16(s);
    pbf[(size_t)b * DD + d] = *reinterpret_cast<ushort*>(&h);
    float q = s * s;
#pragma unroll
    for (int o = 1; o < 64; o <<= 1) q += __shfl_xor(q, o);
    if ((d & 63) == 0) wp[d >> 6] = q;
    __syncthreads();
    if (d == 0) y2[b] = wp[0] + wp[1] + wp[2] + wp[3] + wp[4] + wp[5];
}

// ---------- kernel 2: hybrid MFMA GEMM (A direct-from-global, P dbuf LDS) ----------
// BM=64: wave (wm,wn) computes 32 queries x 128 classes; acc[2][8] = 64 regs.
__global__ __launch_bounds__(256, 3) void main_kernel(const float* __restrict__ reps,
                                                      const ushort* __restrict__ pbf,
                                                      const float* __restrict__ y2g,
                                                      float* __restrict__ out) {
    __shared__ ushort p_lds[2][NCLS * PSTR];  // 2 x 20480 B
    __shared__ float pmx[BM][2];
    __shared__ float pse[BM][2];
    __shared__ float cred[4];

    const int t = threadIdx.x;
    const int v = blockIdx.y;
    const int q0 = blockIdx.x * BM;
    const int wave = t >> 6;
    const int lane = t & 63;
    const int col = lane & 15;   // MFMA m/n index
    const int quad = lane >> 4;  // MFMA k-oct / C row group
    const int wm = wave >> 1;    // query half (32)
    const int wn = wave & 1;     // class half (128)

    // A sources: lane owns query rows q0+wm*32+col and +16 more; k-oct = quad*8
    const int r0 = q0 + wm * 32 + col;
    const int r1 = r0 + 16;
    const float* a0 = reps +
        (size_t)((r0 / NQRY) * PER_CLASS + NSUP + (r0 % NQRY)) * (NVIEW * DD) + v * DD + quad * 8;
    const float* a1 = reps +
        (size_t)((r1 / NQRY) * PER_CLASS + NSUP + (r1 % NQRY)) * (NVIEW * DD) + v * DD + quad * 8;
    // P staging: 1 thread per class row, 64 B per k-tile (coalesced)
    const ushort* psrc = pbf + (size_t)(v * NCLS + t) * DD;

    floatx4 acc[2][8];
#pragma unroll
    for (int m = 0; m < 2; ++m)
#pragma unroll
        for (int nt = 0; nt < 8; ++nt) acc[m][nt] = (floatx4)0.f;

    float4 qf[4];
    uint4 pl[4];

#define ALOAD(kt)                                                          \
    do {                                                                   \
        qf[0] = *(const float4*)(a0 + (kt) * BK);                          \
        qf[1] = *(const float4*)(a0 + (kt) * BK + 4);                      \
        qf[2] = *(const float4*)(a1 + (kt) * BK);                          \
        qf[3] = *(const float4*)(a1 + (kt) * BK + 4);                      \
    } while (0)

#define PLOAD(kt)                                                          \
    do {                                                                   \
        _Pragma("unroll") for (int i = 0; i < 4; ++i)                      \
            pl[i] = *((const uint4*)(psrc + (kt) * BK) + i);               \
    } while (0)

#define PSTAGE(b)                                                          \
    do {                                                                   \
        _Pragma("unroll") for (int i = 0; i < 4; ++i)                      \
            *(uint4*)&p_lds[b][t * PSTR + i * 8] = pl[i];                  \
    } while (0)

    ALOAD(0);
    PLOAD(0);
    PSTAGE(0);
    PLOAD(1);
    BARRIER();

#pragma unroll
    for (int kt = 0; kt < NKT; ++kt) {
        FragU A0, A1;
        A0.u.x = cvt2bf(qf[0].x, qf[0].y); A0.u.y = cvt2bf(qf[0].z, qf[0].w);
        A0.u.z = cvt2bf(qf[1].x, qf[1].y); A0.u.w = cvt2bf(qf[1].z, qf[1].w);
        A1.u.x = cvt2bf(qf[2].x, qf[2].y); A1.u.y = cvt2bf(qf[2].z, qf[2].w);
        A1.u.z = cvt2bf(qf[3].x, qf[3].y); A1.u.w = cvt2bf(qf[3].z, qf[3].w);
        if (kt < NKT - 1) ALOAD(kt + 1);  // in flight across COMPUTE + barrier

#pragma unroll
        for (int nt = 0; nt < 8; ++nt) {
            FragU B;
            B.u = *(const uint4*)&p_lds[kt & 1][(wn * 128 + nt * 16 + col) * PSTR + quad * 8];
            acc[0][nt] = __builtin_amdgcn_mfma_f32_16x16x32_bf16(A0.s, B.s, acc[0][nt], 0, 0, 0);
            acc[1][nt] = __builtin_amdgcn_mfma_f32_16x16x32_bf16(A1.s, B.s, acc[1][nt], 0, 0, 0);
        }
        if (kt < NKT - 1) {
            PSTAGE((kt + 1) & 1);          // vmcnt wait for P(kt+1) lands here
            if (kt < NKT - 2) PLOAD(kt + 2);
            BARRIER();
        }
    }

    // ---- epilogue: per-wave 128-class partials, cross-half combine via LDS ----
    float y2c[8];
#pragma unroll
    for (int nt = 0; nt < 8; ++nt) y2c[nt] = y2g[v * NCLS + wn * 128 + nt * 16 + col];

    float corr = 0.f;
#pragma unroll
    for (int mt = 0; mt < 2; ++mt) {
#pragma unroll
        for (int r = 0; r < 4; ++r) {
            const int qloc = wm * 32 + mt * 16 + quad * 4 + r;
            const int n = q0 + qloc;
            const int cn = n / NQRY;
            float s[8];
            float mx = -1e30f;
#pragma unroll
            for (int nt = 0; nt < 8; ++nt) {
                s[nt] = 2.f * acc[mt][nt][r] - y2c[nt];
                mx = fmaxf(mx, s[nt]);
                if (cn == wn * 128 + nt * 16 + col) corr += s[nt];
            }
#pragma unroll
            for (int o = 1; o < 16; o <<= 1) mx = fmaxf(mx, __shfl_xor(mx, o));
            float e = 0.f;
#pragma unroll
            for (int nt = 0; nt < 8; ++nt) e += __expf(s[nt] - mx);
#pragma unroll
            for (int o = 1; o < 16; o <<= 1) e += __shfl_xor(e, o);
            if (col == 0) { pmx[qloc][wn] = mx; pse[qloc][wn] = e; }
        }
    }
#pragma unroll
    for (int o = 1; o < 64; o <<= 1) corr += __shfl_xor(corr, o);
    if (lane == 0) cred[wave] = corr;
    __syncthreads();

    float lval = 0.f;
    if (t < BM) {
        float m0 = pmx[t][0], m1 = pmx[t][1];
        float M = fmaxf(m0, m1);
        float E = pse[t][0] * __expf(m0 - M) + pse[t][1] * __expf(m1 - M);
        lval = M + __logf(E);
    }
#pragma unroll
    for (int o = 1; o < 64; o <<= 1) lval += __shfl_xor(lval, o);
    if (t == 0) {
        float tot = lval - (cred[0] + cred[1] + cred[2] + cred[3]);
        atomicAdd(out, tot * (1.f / (float)(NQ_TOT * NVIEW)));
    }
}

extern "C" void kernel_launch(void* const* d_in, const int* in_sizes, int n_in,
                              void* d_out, int out_size, void* d_ws, size_t ws_size,
                              hipStream_t stream) {
    const float* reps = (const float*)d_in[0];
    float* ws = (float*)d_ws;
    ushort* pbf = (ushort*)ws;                      // 196608 ushorts
    float* y2 = (float*)(pbf + NVIEW * NCLS * DD);  // 512 floats
    float* out = (float*)d_out;

    hipMemsetAsync(out, 0, sizeof(float), stream);
    proto_kernel<<<dim3(NVIEW * NCLS), dim3(DD), 0, stream>>>(reps, pbf, y2);
    main_kernel<<<dim3(NQ_TOT / BM, NVIEW), dim3(256), 0, stream>>>(reps, pbf, y2, out);
}